// Round 2
// baseline (671.129 us; speedup 1.0000x reference)
//
#include <hip/hip_runtime.h>
#include <math.h>
#include <stdint.h>

#define NLV 16

struct Params {
  float scale[NLV];
  uint32_t res[NLV];
  uint32_t msize[NLV];
  uint32_t offset[NLV];
};

__global__ __launch_bounds__(256) void hash_enc_kernel(
    const float* __restrict__ positions,
    const float* __restrict__ table,
    float* __restrict__ out,
    Params prm, int n)
{
  int p = blockIdx.x * 256 + threadIdx.x;
  if (p >= n) return;

  float x = (positions[3*p+0] + 1.0f) * 0.5f;
  float y = (positions[3*p+1] + 1.0f) * 0.5f;
  float z = (positions[3*p+2] + 1.0f) * 0.5f;

  float acc[32];

  #pragma unroll
  for (int l = 0; l < NLV; ++l) {
    const float s = prm.scale[l];
    const uint32_t res = prm.res[l];
    const uint32_t ms = prm.msize[l];
    const uint32_t off = prm.offset[l];

    float px = x * s + 0.5f;
    float py = y * s + 0.5f;
    float pz = z * s + 0.5f;
    float fx = floorf(px), fy = floorf(py), fz = floorf(pz);
    float tx = px - fx, ty = py - fy, tz = pz - fz;
    uint32_t gx = (uint32_t)fx, gy = (uint32_t)fy, gz = (uint32_t)fz;

    float wx[2] = {1.0f - tx, tx};
    float wy[2] = {1.0f - ty, ty};
    float wz[2] = {1.0f - tz, tz};

    float f0 = 0.0f, f1 = 0.0f;
    #pragma unroll
    for (int c = 0; c < 8; ++c) {
      uint32_t cx = gx + (c & 1u);
      uint32_t cy = gy + ((c >> 1) & 1u);
      uint32_t cz = gz + ((c >> 2) & 1u);
      uint32_t h;
      if (l < 6) {
        // dense: index = x + y*res + z*res^2 ; guaranteed h < 2*msize
        h = cx + cy * res + cz * res * res;
        if (h >= ms) h -= ms;
      } else {
        // hashed: msize is 2^19
        h = cx ^ (cy * 2654435761u) ^ (cz * 805459861u);
        h &= (ms - 1u);
      }
      float w = (wx[c & 1u] * wy[(c >> 1) & 1u]) * wz[(c >> 2) & 1u];
      const float2 t = *reinterpret_cast<const float2*>(table + 2u * (h + off));
      f0 += w * t.x;
      f1 += w * t.y;
    }
    acc[2*l]   = f0;
    acc[2*l+1] = f1;
  }

  float4* o = reinterpret_cast<float4*>(out + (size_t)p * 32u);
  #pragma unroll
  for (int k = 0; k < 8; ++k)
    o[k] = make_float4(acc[4*k+0], acc[4*k+1], acc[4*k+2], acc[4*k+3]);
}

extern "C" void kernel_launch(void* const* d_in, const int* in_sizes, int n_in,
                              void* d_out, int out_size, void* d_ws, size_t ws_size,
                              hipStream_t stream) {
  const float* positions = (const float*)d_in[0];
  const float* table     = (const float*)d_in[1];
  float* out             = (float*)d_out;
  int n = in_sizes[0] / 3;

  // Recompute level metadata exactly as the reference's _level_meta() /
  // _encode_level() do (f64 exp/log, f32 cast for the encode-path scale).
  Params prm;
  const double lnb = log(1.3195079565048218);
  uint32_t off = 0;
  for (int l = 0; l < NLV; ++l) {
    double sd = 16.0 * exp((double)l * lnb) - 1.0;
    uint32_t res_meta = (uint32_t)ceil(sd) + 1u;      // _level_meta resolution
    uint64_t p3 = (uint64_t)res_meta * res_meta * res_meta;
    uint64_t ps = (p3 % 8ull) ? ((p3 + 7ull) / 8ull) * 8ull : p3;
    if (ps > (1ull << 19)) ps = 1ull << 19;
    float sf = (float)sd;                             // np.float32(scale)
    uint32_t res_enc = (uint32_t)(ceilf(sf) + 1.0f);  // encode-path resolution
    prm.scale[l]  = sf;
    prm.res[l]    = res_enc;
    prm.msize[l]  = (uint32_t)ps;
    prm.offset[l] = off;
    off += (uint32_t)ps;
  }

  dim3 grid((n + 255) / 256), block(256);
  hipLaunchKernelGGL(hash_enc_kernel, grid, block, 0, stream,
                     positions, table, out, prm, n);
}

// Round 3
// 481.509 us; speedup vs baseline: 1.3938x; 1.3938x over previous
//
#include <hip/hip_runtime.h>
#include <math.h>
#include <stdint.h>

#define NLV 16
#define NDENSE 6
#define NHASH 10

struct Params {          // all 16 levels (fallback kernel)
  float scale[NLV];
  uint32_t res[NLV];
  uint32_t msize[NLV];
  uint32_t offset[NLV];
};

struct ParamsD {         // dense levels 0..5
  float scale[NDENSE];
  uint32_t res[NDENSE];
  uint32_t msize[NDENSE];
  uint32_t offset[NDENSE];
};

// ---------- per-hashed-level pass: tmp[p] = feat2(level) ----------
__global__ __launch_bounds__(256) void hash_level_kernel(
    const float* __restrict__ positions,
    const float* __restrict__ tbl,      // table already offset to this level
    float2* __restrict__ tmp,
    float scale, uint32_t mask, int n)
{
  int p = blockIdx.x * 256 + threadIdx.x;
  if (p >= n) return;

  float x = (positions[3*p+0] + 1.0f) * 0.5f;
  float y = (positions[3*p+1] + 1.0f) * 0.5f;
  float z = (positions[3*p+2] + 1.0f) * 0.5f;

  float px = x * scale + 0.5f;
  float py = y * scale + 0.5f;
  float pz = z * scale + 0.5f;
  float fx = floorf(px), fy = floorf(py), fz = floorf(pz);
  float tx = px - fx, ty = py - fy, tz = pz - fz;
  uint32_t gx = (uint32_t)fx, gy = (uint32_t)fy, gz = (uint32_t)fz;

  float wx[2] = {1.0f - tx, tx};
  float wy[2] = {1.0f - ty, ty};
  float wz[2] = {1.0f - tz, tz};

  float f0 = 0.0f, f1 = 0.0f;
  #pragma unroll
  for (int c = 0; c < 8; ++c) {
    uint32_t cx = gx + (c & 1u);
    uint32_t cy = gy + ((c >> 1) & 1u);
    uint32_t cz = gz + ((c >> 2) & 1u);
    uint32_t h = (cx ^ (cy * 2654435761u) ^ (cz * 805459861u)) & mask;
    float w = (wx[c & 1u] * wy[(c >> 1) & 1u]) * wz[(c >> 2) & 1u];
    const float2 t = *reinterpret_cast<const float2*>(tbl + 2u * h);
    f0 += w * t.x;
    f1 += w * t.y;
  }
  tmp[p] = make_float2(f0, f1);
}

// ---------- dense levels inline + pack everything ----------
__global__ __launch_bounds__(256) void dense_pack_kernel(
    const float* __restrict__ positions,
    const float* __restrict__ table,
    const float2* __restrict__ tmp,     // [NHASH][n] level-major
    float* __restrict__ out,
    ParamsD prm, int n)
{
  int p = blockIdx.x * 256 + threadIdx.x;
  if (p >= n) return;

  float x = (positions[3*p+0] + 1.0f) * 0.5f;
  float y = (positions[3*p+1] + 1.0f) * 0.5f;
  float z = (positions[3*p+2] + 1.0f) * 0.5f;

  float acc[2*NDENSE];

  #pragma unroll
  for (int l = 0; l < NDENSE; ++l) {
    const float s = prm.scale[l];
    const uint32_t res = prm.res[l];
    const uint32_t ms = prm.msize[l];
    const uint32_t off = prm.offset[l];

    float px = x * s + 0.5f;
    float py = y * s + 0.5f;
    float pz = z * s + 0.5f;
    float fx = floorf(px), fy = floorf(py), fz = floorf(pz);
    float tx = px - fx, ty = py - fy, tz = pz - fz;
    uint32_t gx = (uint32_t)fx, gy = (uint32_t)fy, gz = (uint32_t)fz;

    float wx[2] = {1.0f - tx, tx};
    float wy[2] = {1.0f - ty, ty};
    float wz[2] = {1.0f - tz, tz};

    float f0 = 0.0f, f1 = 0.0f;
    #pragma unroll
    for (int c = 0; c < 8; ++c) {
      uint32_t cx = gx + (c & 1u);
      uint32_t cy = gy + ((c >> 1) & 1u);
      uint32_t cz = gz + ((c >> 2) & 1u);
      uint32_t h = cx + cy * res + cz * res * res;  // dense index
      if (h >= ms) h -= ms;                          // h < 2*ms always
      float w = (wx[c & 1u] * wy[(c >> 1) & 1u]) * wz[(c >> 2) & 1u];
      const float2 t = *reinterpret_cast<const float2*>(table + 2u * (h + off));
      f0 += w * t.x;
      f1 += w * t.y;
    }
    acc[2*l]   = f0;
    acc[2*l+1] = f1;
  }

  // hashed-level temps (coalesced: wave reads 64 consecutive float2 per level)
  float2 h6  = tmp[0*(size_t)n + p];
  float2 h7  = tmp[1*(size_t)n + p];
  float2 h8  = tmp[2*(size_t)n + p];
  float2 h9  = tmp[3*(size_t)n + p];
  float2 h10 = tmp[4*(size_t)n + p];
  float2 h11 = tmp[5*(size_t)n + p];
  float2 h12 = tmp[6*(size_t)n + p];
  float2 h13 = tmp[7*(size_t)n + p];
  float2 h14 = tmp[8*(size_t)n + p];
  float2 h15 = tmp[9*(size_t)n + p];

  float4* o = reinterpret_cast<float4*>(out + (size_t)p * 32u);
  o[0] = make_float4(acc[0], acc[1], acc[2],  acc[3]);
  o[1] = make_float4(acc[4], acc[5], acc[6],  acc[7]);
  o[2] = make_float4(acc[8], acc[9], acc[10], acc[11]);
  o[3] = make_float4(h6.x,  h6.y,  h7.x,  h7.y);
  o[4] = make_float4(h8.x,  h8.y,  h9.x,  h9.y);
  o[5] = make_float4(h10.x, h10.y, h11.x, h11.y);
  o[6] = make_float4(h12.x, h12.y, h13.x, h13.y);
  o[7] = make_float4(h14.x, h14.y, h15.x, h15.y);
}

// ---------- fallback: single fused kernel (R2 version) ----------
__global__ __launch_bounds__(256) void hash_enc_kernel(
    const float* __restrict__ positions,
    const float* __restrict__ table,
    float* __restrict__ out,
    Params prm, int n)
{
  int p = blockIdx.x * 256 + threadIdx.x;
  if (p >= n) return;

  float x = (positions[3*p+0] + 1.0f) * 0.5f;
  float y = (positions[3*p+1] + 1.0f) * 0.5f;
  float z = (positions[3*p+2] + 1.0f) * 0.5f;

  float acc[32];

  #pragma unroll
  for (int l = 0; l < NLV; ++l) {
    const float s = prm.scale[l];
    const uint32_t res = prm.res[l];
    const uint32_t ms = prm.msize[l];
    const uint32_t off = prm.offset[l];

    float px = x * s + 0.5f;
    float py = y * s + 0.5f;
    float pz = z * s + 0.5f;
    float fx = floorf(px), fy = floorf(py), fz = floorf(pz);
    float tx = px - fx, ty = py - fy, tz = pz - fz;
    uint32_t gx = (uint32_t)fx, gy = (uint32_t)fy, gz = (uint32_t)fz;

    float wx[2] = {1.0f - tx, tx};
    float wy[2] = {1.0f - ty, ty};
    float wz[2] = {1.0f - tz, tz};

    float f0 = 0.0f, f1 = 0.0f;
    #pragma unroll
    for (int c = 0; c < 8; ++c) {
      uint32_t cx = gx + (c & 1u);
      uint32_t cy = gy + ((c >> 1) & 1u);
      uint32_t cz = gz + ((c >> 2) & 1u);
      uint32_t h;
      if (l < NDENSE) {
        h = cx + cy * res + cz * res * res;
        if (h >= ms) h -= ms;
      } else {
        h = cx ^ (cy * 2654435761u) ^ (cz * 805459861u);
        h &= (ms - 1u);
      }
      float w = (wx[c & 1u] * wy[(c >> 1) & 1u]) * wz[(c >> 2) & 1u];
      const float2 t = *reinterpret_cast<const float2*>(table + 2u * (h + off));
      f0 += w * t.x;
      f1 += w * t.y;
    }
    acc[2*l]   = f0;
    acc[2*l+1] = f1;
  }

  float4* o = reinterpret_cast<float4*>(out + (size_t)p * 32u);
  #pragma unroll
  for (int k = 0; k < 8; ++k)
    o[k] = make_float4(acc[4*k+0], acc[4*k+1], acc[4*k+2], acc[4*k+3]);
}

extern "C" void kernel_launch(void* const* d_in, const int* in_sizes, int n_in,
                              void* d_out, int out_size, void* d_ws, size_t ws_size,
                              hipStream_t stream) {
  const float* positions = (const float*)d_in[0];
  const float* table     = (const float*)d_in[1];
  float* out             = (float*)d_out;
  int n = in_sizes[0] / 3;

  // Level metadata, exactly mirroring the reference (f64 exp/log; f32 cast
  // for the encode-path scale; level 5 is dense with res=65 due to the
  // B_SCALE^5 = 4.0000007 float quirk).
  Params prm;
  const double lnb = log(1.3195079565048218);
  uint32_t off = 0;
  for (int l = 0; l < NLV; ++l) {
    double sd = 16.0 * exp((double)l * lnb) - 1.0;
    uint32_t res_meta = (uint32_t)ceil(sd) + 1u;
    uint64_t p3 = (uint64_t)res_meta * res_meta * res_meta;
    uint64_t ps = (p3 % 8ull) ? ((p3 + 7ull) / 8ull) * 8ull : p3;
    if (ps > (1ull << 19)) ps = 1ull << 19;
    float sf = (float)sd;
    uint32_t res_enc = (uint32_t)(ceilf(sf) + 1.0f);
    prm.scale[l]  = sf;
    prm.res[l]    = res_enc;
    prm.msize[l]  = (uint32_t)ps;
    prm.offset[l] = off;
    off += (uint32_t)ps;
  }

  dim3 grid((n + 255) / 256), block(256);
  size_t ws_needed = (size_t)NHASH * (size_t)n * sizeof(float2);

  if (ws_size >= ws_needed) {
    float2* tmp = (float2*)d_ws;
    // one pass per hashed level: only that level's 4 MB table is hot in L2
    for (int l = NDENSE; l < NLV; ++l) {
      hipLaunchKernelGGL(hash_level_kernel, grid, block, 0, stream,
                         positions, table + 2u * prm.offset[l],
                         tmp + (size_t)(l - NDENSE) * n,
                         prm.scale[l], prm.msize[l] - 1u, n);
    }
    ParamsD pd;
    for (int l = 0; l < NDENSE; ++l) {
      pd.scale[l] = prm.scale[l]; pd.res[l] = prm.res[l];
      pd.msize[l] = prm.msize[l]; pd.offset[l] = prm.offset[l];
    }
    hipLaunchKernelGGL(dense_pack_kernel, grid, block, 0, stream,
                       positions, table, tmp, out, pd, n);
  } else {
    // ws too small: correct (slower) single-kernel fallback
    hipLaunchKernelGGL(hash_enc_kernel, grid, block, 0, stream,
                       positions, table, out, prm, n);
  }
}